// Round 1
// baseline (299.865 us; speedup 1.0000x reference)
//
#include <hip/hip_runtime.h>

// Triaffine: span[b,x,y,z] = sum_{i,o,j} start[b,x,i] W[i,o,j] end[b,y,j] cls[b,z,o]
// B=8, L=256, Z=16, H=256.  Contraction order: o first (Z=16 small), then i, then j.
//   K1: Wc[bz,i,j]  = sum_o cls[bz,o] * W[i,o,j]        (batched over i)
//   K2: T [bz,x,j]  = sum_i start[b,x,i] * Wc[bz,i,j]   (batched over bz)
//   K3: tmp[bz,x,y] = sum_j T[bz,x,j] * end[b,y,j]      (batched over bz, A@B^T)
//   K4: out[b,x,y,z] = tmp[(b,z),x,y]                    (z-transpose, LDS tiled)
// Total 12.9 GFLOP fp32 (vs 142 GF reference order). fp32 vector ALU (no fp32 MFMA).
// Scratch: Wc in ws[0:33.5MB]; T lives in d_out (dead before K4 writes); tmp reuses Wc slot.

#define BM 128
#define BN 128
#define BK 16
#define LDP (BN + 4)   // padded LDS row (132 floats = 528B, 16B-aligned)

template<bool BT>
__global__ __launch_bounds__(256, 4)
void gemm_tile(const float* __restrict__ Ab, const float* __restrict__ Bb,
               float* __restrict__ Cb,
               int lda, int ldb, int ldc,
               long aBS, int aSh, long bBS, int bSh, long cBS, int K)
{
    __shared__ float As[BK][LDP];
    __shared__ float Bs[BK][LDP];

    const int tid   = threadIdx.x;
    const int batch = blockIdx.z;
    const float* A = Ab + (long)(batch >> aSh) * aBS;
    const float* B = Bb + (long)(batch >> bSh) * bBS;
    float*       C = Cb + (long)batch * cBS;

    const int row0 = blockIdx.y * BM;
    const int col0 = blockIdx.x * BN;

    // staging indices
    const int am = tid >> 1;          // 0..127 (row of A tile)
    const int ak = (tid & 1) * 8;     // 0 or 8 (k offset, 2x float4)
    // compute indices: 16x16 threads, 8x8 outputs each
    const int tm = tid >> 4;          // 0..15
    const int tn = tid & 15;          // 0..15

    float acc[8][8] = {};

    for (int k0 = 0; k0 < K; k0 += BK) {
        // --- A tile: BM x BK -> As[k][m] (transposed store, 2-way conflict = free)
        {
            const float* ap = A + (long)(row0 + am) * lda + k0 + ak;
            float4 a0 = *(const float4*)(ap);
            float4 a1 = *(const float4*)(ap + 4);
            As[ak + 0][am] = a0.x; As[ak + 1][am] = a0.y;
            As[ak + 2][am] = a0.z; As[ak + 3][am] = a0.w;
            As[ak + 4][am] = a1.x; As[ak + 5][am] = a1.y;
            As[ak + 6][am] = a1.z; As[ak + 7][am] = a1.w;
        }
        // --- B tile: BK x BN -> Bs[k][n]
        if (!BT) {
            const int bk = tid >> 4;         // 0..15
            const int bn = (tid & 15) * 8;   // 0..120
            const float* bp = B + (long)(k0 + bk) * ldb + col0 + bn;
            *(float4*)&Bs[bk][bn]     = *(const float4*)(bp);
            *(float4*)&Bs[bk][bn + 4] = *(const float4*)(bp + 4);
        } else {
            // B^T[k][n] = B[n*ldb + k] : load along k, transpose into LDS
            const int bn  = tid >> 1;        // 0..127 (n)
            const int bkq = (tid & 1) * 8;   // 0 or 8
            const float* bp = B + (long)(col0 + bn) * ldb + k0 + bkq;
            float4 b0 = *(const float4*)(bp);
            float4 b1 = *(const float4*)(bp + 4);
            Bs[bkq + 0][bn] = b0.x; Bs[bkq + 1][bn] = b0.y;
            Bs[bkq + 2][bn] = b0.z; Bs[bkq + 3][bn] = b0.w;
            Bs[bkq + 4][bn] = b1.x; Bs[bkq + 5][bn] = b1.y;
            Bs[bkq + 6][bn] = b1.z; Bs[bkq + 7][bn] = b1.w;
        }
        __syncthreads();

#pragma unroll
        for (int kk = 0; kk < BK; ++kk) {
            float4 a0 = *(const float4*)&As[kk][tm * 8];
            float4 a1 = *(const float4*)&As[kk][tm * 8 + 4];
            float4 b0 = *(const float4*)&Bs[kk][tn * 8];
            float4 b1 = *(const float4*)&Bs[kk][tn * 8 + 4];
            float ar[8] = {a0.x,a0.y,a0.z,a0.w,a1.x,a1.y,a1.z,a1.w};
            float br[8] = {b0.x,b0.y,b0.z,b0.w,b1.x,b1.y,b1.z,b1.w};
#pragma unroll
            for (int r = 0; r < 8; ++r)
#pragma unroll
                for (int c = 0; c < 8; ++c)
                    acc[r][c] = fmaf(ar[r], br[c], acc[r][c]);
        }
        __syncthreads();
    }

    // --- epilogue: coalesced float4 stores
#pragma unroll
    for (int r = 0; r < 8; ++r) {
        float* cp = C + (long)(row0 + tm * 8 + r) * ldc + col0 + tn * 8;
        float4 v0 = {acc[r][0], acc[r][1], acc[r][2], acc[r][3]};
        float4 v1 = {acc[r][4], acc[r][5], acc[r][6], acc[r][7]};
        *(float4*)(cp)     = v0;
        *(float4*)(cp + 4) = v1;
    }
}

// tmp[(b*16+z), x, y] -> out[((b*256+x)*256+y)*16+z]
// one block per (b,x): reads 16 coalesced z-rows of 256 y, writes 16KB contiguous.
__global__ __launch_bounds__(256)
void ztranspose(const float* __restrict__ tmp, float* __restrict__ out)
{
    __shared__ float lds[256][17];
    const int tid = threadIdx.x;
    const int b = blockIdx.x >> 8;
    const int x = blockIdx.x & 255;

#pragma unroll
    for (int z = 0; z < 16; ++z) {
        lds[tid][z] = tmp[((long)(b * 16 + z) * 256 + x) * 256 + tid];
    }
    __syncthreads();

    float* op = out + (long)(b * 256 + x) * 4096;
#pragma unroll
    for (int q = 0; q < 4; ++q) {
        const int y  = q * 64 + (tid >> 2);
        const int z0 = (tid & 3) * 4;
        float4 v = { lds[y][z0], lds[y][z0 + 1], lds[y][z0 + 2], lds[y][z0 + 3] };
        *(float4*)(op + (q * 256 + tid) * 4) = v;
    }
}

extern "C" void kernel_launch(void* const* d_in, const int* in_sizes, int n_in,
                              void* d_out, int out_size, void* d_ws, size_t ws_size,
                              hipStream_t stream)
{
    const float* start = (const float*)d_in[0];  // [8,256,256]
    const float* endl  = (const float*)d_in[1];  // [8,256,256]
    const float* cls   = (const float*)d_in[2];  // [8,16,256]
    const float* W     = (const float*)d_in[3];  // [256,256,256] (i,o,j)
    float* out = (float*)d_out;                  // [8,256,256,16]

    float* Wc  = (float*)d_ws;   // [128][256][256] = 33.5 MB
    float* T   = out;            // [128][256][256] reuses d_out (dead before K4 writes)
    float* tmp = Wc;             // [128][256][256] reuses Wc slot (Wc dead after K2)

    // K1: Wc[bz,i,j] = sum_o cls[bz,o] * W[i,o,j]
    //     batch=i (256): A=cls (M=128,lda=256, shared), B=W+i*65536 (ldb=256),
    //     C=Wc+i*256 (ldc=65536, row=bz)
    hipLaunchKernelGGL((gemm_tile<false>), dim3(2, 1, 256), dim3(256), 0, stream,
        cls, W, Wc, 256, 256, 65536,
        0L, 0, 65536L, 0, 256L, 256);

    // K2: T[bz,x,j] = sum_i start[b,x,i] * Wc[bz,i,j]   batch=bz (128), b=bz>>4
    hipLaunchKernelGGL((gemm_tile<false>), dim3(2, 2, 128), dim3(256), 0, stream,
        start, Wc, T, 256, 256, 256,
        65536L, 4, 65536L, 0, 65536L, 256);

    // K3: tmp[bz,x,y] = sum_j T[bz,x,j] * end[b,y,j]    batch=bz (128), A@B^T
    hipLaunchKernelGGL((gemm_tile<true>), dim3(2, 2, 128), dim3(256), 0, stream,
        T, endl, tmp, 256, 256, 256,
        65536L, 0, 65536L, 4, 65536L, 256);

    // K4: z-transpose
    hipLaunchKernelGGL(ztranspose, dim3(2048), dim3(256), 0, stream, tmp, out);
}

// Round 3
// 157.321 us; speedup vs baseline: 1.9061x; 1.9061x over previous
//
#include <hip/hip_runtime.h>
#include <hip/hip_bf16.h>

// Triaffine span[b,x,y,z] = sum_{i,o,j} start[b,x,i] W[i,o,j] end[b,y,j] cls[b,z,o]
// B=8, L=256, Z=16, H=256. Contraction order o -> i -> j (12.9 GF), bf16 MFMA.
//   K1: Wc[bz,i,j]  = sum_o cls[bz,o] * W[i,o,j]    batch=i, B=W k-rows (TRANS stage)
//   K2: T [bz,x,j]  = sum_i start[b,x,i] * Wc[bz,i,j] batch=bz, B=Wc k-rows (TRANS)
//   K3: tmp[bz,x,y] = sum_j T[bz,x,j] * end[b,y,j]  batch=bz, both natural (A@B^T)
//   K4: out[b,x,y,z] = tmp[(b,z),x,y]
// Scratch: Wc bf16 ws[0:16.7MB]; T bf16 in d_out bytes[0:16.7MB] (dead before K4);
//          tmp fp32 ws[0:33.5MB] (over dead Wc). ws >= 33.5MB proven in round 1.
// FIX vs round 2: BTRANS staging covers the full 32x128 tile in ONE pass
// (bk2 x bn0 = 32 k x 128 n); it was wrongly inside the 2-iter `it` loop,
// reading OOB global columns and writing ~5KB past the Bs LDS buffer.

typedef __attribute__((ext_vector_type(8))) short      bf16x8;
typedef __attribute__((ext_vector_type(8))) unsigned short u16x8;
typedef __attribute__((ext_vector_type(4))) float      f32x4;

#define LDST 40   // LDS row stride in shorts: 80 B (16B-aligned rows, ~2-way read banks)

__device__ __forceinline__ unsigned short f2bf(float f) {
    unsigned u = __builtin_bit_cast(unsigned, f);
    u += 0x7fff + ((u >> 16) & 1);            // RNE
    return (unsigned short)(u >> 16);
}

// 128x128 tile, K=256 (8 steps of BK=32), 256 threads = 4 waves (2x2 quadrants of 64x64).
// A global: [m][k] row-major (fp32 or bf16). B global: BTRANS ? [k][n] : [n][k].
template<bool AB16, bool BB16, bool BTRANS, bool CB16>
__global__ __launch_bounds__(256)
void gemm_mfma(const void* __restrict__ Abv, const void* __restrict__ Bbv,
               void* __restrict__ Cbv,
               int lda, int ldb, int ldc,
               long aBS, int aSh, long bBS, int bSh, long cBS)
{
    __shared__ unsigned short As[128 * LDST];
    __shared__ unsigned short Bs[128 * LDST];

    const int tid  = threadIdx.x;
    const int bz   = blockIdx.z;
    const int row0 = blockIdx.y * 128;
    const int col0 = blockIdx.x * 128;

    const float*          Af = (const float*)Abv          + (long)(bz >> aSh) * aBS;
    const unsigned short* Ah = (const unsigned short*)Abv + (long)(bz >> aSh) * aBS;
    const float*          Bf = (const float*)Bbv          + (long)(bz >> bSh) * bBS;
    const unsigned short* Bh = (const unsigned short*)Bbv + (long)(bz >> bSh) * bBS;
    float*          Cf = (float*)Cbv          + (long)bz * cBS;
    unsigned short* Ch = (unsigned short*)Cbv + (long)bz * cBS;

    // staging indices
    const int ar  = tid >> 2;        // 0..63 : row (A / natural-B), +64 on iter 1
    const int akc = tid & 3;         // k-chunk (8 elems)
    const int bk2 = (tid & 15) * 2;  // TRANS: k-row pair (0..30)
    const int bn0 = (tid >> 4) * 8;  // TRANS: n group (0..120) -> full 128 n in one pass

    // compute indices
    const int wid = tid >> 6, lane = tid & 63;
    const int wm = wid >> 1, wn = wid & 1;
    const int lr = lane & 15, lg = lane >> 4;

    f32x4 acc[4][4] = {};

    // prefetch registers
    float4 aPf[2][2]; u16x8 aPh[2];      // A: 2 row-halves
    float4 bNf[2][2]; u16x8 bNh[2];      // B natural: 2 row-halves
    float4 bTf[4];    u16x8 bTh[2];      // B trans: single pass, 2 k-rows x 8 n

    auto LOAD = [&](int k0) {
#pragma unroll
        for (int it = 0; it < 2; ++it) {
            if constexpr (!AB16) {
                const float* p = Af + (long)(row0 + ar + 64 * it) * lda + k0 + akc * 8;
                aPf[it][0] = *(const float4*)p;
                aPf[it][1] = *(const float4*)(p + 4);
            } else {
                aPh[it] = *(const u16x8*)(Ah + (long)(row0 + ar + 64 * it) * lda + k0 + akc * 8);
            }
            if constexpr (!BTRANS) {
                if constexpr (!BB16) {
                    const float* p = Bf + (long)(col0 + ar + 64 * it) * ldb + k0 + akc * 8;
                    bNf[it][0] = *(const float4*)p;
                    bNf[it][1] = *(const float4*)(p + 4);
                } else {
                    bNh[it] = *(const u16x8*)(Bh + (long)(col0 + ar + 64 * it) * ldb + k0 + akc * 8);
                }
            }
        }
        if constexpr (BTRANS) {          // single pass: 2 k-rows (bk2, bk2+1) x 8 n
            if constexpr (!BB16) {
                const float* p = Bf + (long)(k0 + bk2) * ldb + col0 + bn0;
                bTf[0] = *(const float4*)p;
                bTf[1] = *(const float4*)(p + 4);
                bTf[2] = *(const float4*)(p + ldb);
                bTf[3] = *(const float4*)(p + ldb + 4);
            } else {
                const unsigned short* p = Bh + (long)(k0 + bk2) * ldb + col0 + bn0;
                bTh[0] = *(const u16x8*)p;
                bTh[1] = *(const u16x8*)(p + ldb);
            }
        }
    };

    auto WRITE = [&]() {
#pragma unroll
        for (int it = 0; it < 2; ++it) {
            // ---- A tile -> As[row][k]
            u16x8 w;
            if constexpr (!AB16) {
                const float* v = (const float*)&aPf[it][0];
#pragma unroll
                for (int e = 0; e < 8; ++e) w[e] = f2bf(v[e]);
            } else {
                w = aPh[it];
            }
            *(u16x8*)(As + (ar + 64 * it) * LDST + akc * 8) = w;

            if constexpr (!BTRANS) {
                u16x8 wb;
                if constexpr (!BB16) {
                    const float* v = (const float*)&bNf[it][0];
#pragma unroll
                    for (int e = 0; e < 8; ++e) wb[e] = f2bf(v[e]);
                } else {
                    wb = bNh[it];
                }
                *(u16x8*)(Bs + (ar + 64 * it) * LDST + akc * 8) = wb;
            }
        }
        if constexpr (BTRANS) {          // pack k-pair into b32, write column-wise
#pragma unroll
            for (int e = 0; e < 8; ++e) {
                unsigned lo, hi;
                if constexpr (!BB16) {
                    const float* v0 = (const float*)&bTf[0]; // k row bk2   (8 floats)
                    const float* v1 = (const float*)&bTf[2]; // k row bk2+1 (8 floats)
                    lo = f2bf(v0[e]); hi = f2bf(v1[e]);
                } else {
                    lo = bTh[0][e]; hi = bTh[1][e];
                }
                *(unsigned*)(Bs + (bn0 + e) * LDST + bk2) = lo | (hi << 16);
            }
        }
    };

    auto COMPUTE = [&]() {
        bf16x8 aF[4], bF[4];
#pragma unroll
        for (int f = 0; f < 4; ++f) {
            aF[f] = *(const bf16x8*)&As[(wm * 64 + f * 16 + lr) * LDST + lg * 8];
            bF[f] = *(const bf16x8*)&Bs[(wn * 64 + f * 16 + lr) * LDST + lg * 8];
        }
#pragma unroll
        for (int fm = 0; fm < 4; ++fm)
#pragma unroll
            for (int fn = 0; fn < 4; ++fn)
                acc[fm][fn] = __builtin_amdgcn_mfma_f32_16x16x32_bf16(
                    aF[fm], bF[fn], acc[fm][fn], 0, 0, 0);
    };

    LOAD(0);
#pragma unroll
    for (int s = 0; s < 8; ++s) {
        WRITE();
        if (s < 7) LOAD((s + 1) * 32);   // issue next-step loads early (overlap compute)
        __syncthreads();
        COMPUTE();
        __syncthreads();
    }

    // epilogue: C/D mapping col=lane&15, row=(lane>>4)*4+q  [m89-verified]
#pragma unroll
    for (int fm = 0; fm < 4; ++fm)
#pragma unroll
        for (int q = 0; q < 4; ++q) {
            const long row = row0 + wm * 64 + fm * 16 + lg * 4 + q;
#pragma unroll
            for (int fn = 0; fn < 4; ++fn) {
                const int col = col0 + wn * 64 + fn * 16 + lr;
                if constexpr (CB16) Ch[row * ldc + col] = f2bf(acc[fm][fn][q]);
                else                Cf[row * ldc + col] = acc[fm][fn][q];
            }
        }
}

// tmp[(b*16+z), x, y] fp32 -> out[((b*256+x)*256+y)*16+z]
__global__ __launch_bounds__(256)
void ztranspose(const float* __restrict__ tmp, float* __restrict__ out)
{
    __shared__ float lds[256][17];
    const int tid = threadIdx.x;
    const int b = blockIdx.x >> 8;
    const int x = blockIdx.x & 255;

#pragma unroll
    for (int z = 0; z < 16; ++z)
        lds[tid][z] = tmp[((long)(b * 16 + z) * 256 + x) * 256 + tid];
    __syncthreads();

    float* op = out + (long)(b * 256 + x) * 4096;
#pragma unroll
    for (int q = 0; q < 4; ++q) {
        const int y  = q * 64 + (tid >> 2);
        const int z0 = (tid & 3) * 4;
        float4 v = { lds[y][z0], lds[y][z0 + 1], lds[y][z0 + 2], lds[y][z0 + 3] };
        *(float4*)(op + (q * 256 + tid) * 4) = v;
    }
}

extern "C" void kernel_launch(void* const* d_in, const int* in_sizes, int n_in,
                              void* d_out, int out_size, void* d_ws, size_t ws_size,
                              hipStream_t stream)
{
    const float* start = (const float*)d_in[0];  // [8,256,256]
    const float* endl  = (const float*)d_in[1];  // [8,256,256]
    const float* cls   = (const float*)d_in[2];  // [8,16,256]
    const float* W     = (const float*)d_in[3];  // [256,256,256] (i,o,j)
    float* out = (float*)d_out;                  // [8,256,256,16]

    unsigned short* Wc  = (unsigned short*)d_ws;   // bf16 [128][256][256] = 16.7 MB
    unsigned short* T   = (unsigned short*)d_out;  // bf16 [128][256][256] in d_out scratch
    float*          tmp = (float*)d_ws;            // fp32 [128][256][256] over dead Wc

    // K1: Wc[bz,i,j] = sum_o cls[bz,o]*W[i,o,j].  batch=i(256). M=128(bz), N=256(j), K=256(o)
    //     A=cls fp32 (shared, lda=256); B=W_i [o][j] TRANS (ldb=256, bBS=65536);
    //     C=Wc bf16: base+i*256, ldc=65536 (row=bz)
    hipLaunchKernelGGL((gemm_mfma<false, false, true, true>), dim3(2, 1, 256), dim3(256), 0, stream,
        (const void*)cls, (const void*)W, (void*)Wc,
        256, 256, 65536, 0L, 0, 65536L, 0, 256L);

    // K2: T[bz,x,j] = sum_i start[b,x,i]*Wc[bz,i,j].  batch=bz(128). M=256,N=256,K=256
    //     A=start fp32 (aBS=65536, b=bz>>4); B=Wc bf16 [i][j] TRANS; C=T bf16
    hipLaunchKernelGGL((gemm_mfma<false, true, true, true>), dim3(2, 2, 128), dim3(256), 0, stream,
        (const void*)start, (const void*)Wc, (void*)T,
        256, 256, 256, 65536L, 4, 65536L, 0, 65536L);

    // K3: tmp[bz,x,y] = sum_j T[bz,x,j]*end[b,y,j].  batch=bz(128). natural A@B^T
    //     A=T bf16; B=end fp32 [y][j] NAT (bBS=65536, b=bz>>4); C=tmp fp32
    hipLaunchKernelGGL((gemm_mfma<true, false, false, false>), dim3(2, 2, 128), dim3(256), 0, stream,
        (const void*)T, (const void*)endl, (void*)tmp,
        256, 256, 256, 65536L, 0, 65536L, 4, 65536L);

    // K4: z-transpose
    hipLaunchKernelGGL(ztranspose, dim3(2048), dim3(256), 0, stream, tmp, out);
}